// Round 5
// baseline (437.800 us; speedup 1.0000x reference)
//
#include <hip/hip_runtime.h>
#include <stdint.h>

#define STEP 0.02f
#define INV_RADIUS (1.0f/1.3f)
#define RADIUS 1.3f

typedef __bf16   bf16x8 __attribute__((ext_vector_type(8)));
typedef float    f32x4  __attribute__((ext_vector_type(4)));
typedef float    f32x2  __attribute__((ext_vector_type(2)));
typedef uint32_t u32x4  __attribute__((ext_vector_type(4)));
typedef uint32_t u32x4a __attribute__((ext_vector_type(4), aligned(8)));

// ---------------- ws layout (bytes) ----------------
#define FT_OFF   0         // F transposed bf16 [z16][y16][x16][c32] = 262144 B
#define W0_OFF   262144    // sig W0  K=32  N=128 : 1kk x 8nt  = 8192 B
#define W1_OFF   270336    // sig W1  K=128 N=128 : 4kk x 8nt  = 32768 B
#define W2_OFF   303104    // sig W2  K=128 N=16  : 4kk x 1nt  = 4096 B
#define C0_OFF   307200    // col W0  K=31->32 (pad at k=16) N=64 : 1x4 = 4096 B
#define C1_OFF   311296    // col W1  K=64 N=64 : 2x4          = 8192 B
#define C2_OFF   319488    // col W2  K=64 N=3->16 : 2x1       = 2048 B (end 321536)
// packed G1: [z][y][x][ch0,ch1,ch2,pad] bf16 = 8 B/cell, 256^3 cells
#define G1T_OFF  321536
#define WS_NEED  (321536ull + 134217728ull)

// ---------------- block LDS (bytes) ----------------
#define FE_BYTES  4096     // per wave: 64 rows x 64B
#define SIG_OFF   8192     // 128 f32 = 512
#define COL_OFF   8704     // 128 x 4 f32 = 2048
#define BLOCK_LDS 10752

#define PRIO1 __builtin_amdgcn_s_setprio(1)
#define PRIO0 __builtin_amdgcn_s_setprio(0)

__device__ __forceinline__ uint32_t pack2(float a, float b){
    uint32_t ua = __float_as_uint(a); ua += 0x7FFFu + ((ua>>16)&1u);
    uint32_t ub = __float_as_uint(b); ub += 0x7FFFu + ((ub>>16)&1u);
    return (ua>>16) | (ub & 0xFFFF0000u);
}
__device__ __forceinline__ float bfl(uint32_t u){ return __uint_as_float(u << 16); }
__device__ __forceinline__ float bfh(uint32_t u){ return __uint_as_float(u & 0xFFFF0000u); }
__device__ __forceinline__ void toidx(float c, float sizem1, int isize,
                                      int& i0, int& i1, float& w){
    float t = (c + 1.f) * 0.5f * sizem1;
    t = fminf(fmaxf(t, 0.f), sizem1);
    float f = floorf(t);
    i0 = (int)f;
    i1 = i0 + 1; if (i1 > isize - 1) i1 = isize - 1;
    w = t - f;
}
__device__ __forceinline__ void lds_fence(){
    asm volatile("s_waitcnt lgkmcnt(0)" ::: "memory");
}
__device__ __forceinline__ uint32_t cvtpk(float lo, float hi){
    uint32_t r;
    asm("v_cvt_pk_bf16_f32 %0, %1, %2" : "=v"(r) : "v"(lo), "v"(hi));
    return r;
}
__device__ __forceinline__ void p32swap(uint32_t& a, uint32_t& b){
    asm("v_permlane32_swap_b32 %0, %1" : "+v"(a), "+v"(b));
}
__device__ __forceinline__ void p16swap(uint32_t& a, uint32_t& b){
    asm("v_permlane16_swap_b32 %0, %1" : "+v"(a), "+v"(b));
}
__device__ __forceinline__ uint32_t pkrelu(float a, float b){
    return cvtpk(fmaxf(a, 0.f), fmaxf(b, 0.f));
}
__device__ __forceinline__ bf16x8 frag_from(uint32_t a, uint32_t b, uint32_t c, uint32_t d){
    union { u32x4 u; bf16x8 h; } cv;
    cv.u = (u32x4){a, b, c, d};
    return cv.h;
}
// D-tiles -> next-layer B-frag in-register transpose (+relu)
__device__ __forceinline__ bf16x8 xpose4(const f32x4& t0, const f32x4& t1){
    uint32_t A = pkrelu(t0[0], t0[1]);
    uint32_t B = pkrelu(t0[2], t0[3]);
    uint32_t C = pkrelu(t1[0], t1[1]);
    uint32_t D = pkrelu(t1[2], t1[3]);
    p32swap(A, C); p16swap(A, C);
    p32swap(B, D); p16swap(B, D);
    return frag_from(A, B, C, D);
}
// x-lerp of one packed (z,y)-row: cells A(dwords 0,1) B(dwords 2,3); xe => x0==255
__device__ __forceinline__ void rowlerp(const u32x4a d, bool xe, float wx,
                                        float& v0, float& v1, float& v2){
    uint32_t a01 = xe ? d[2] : d[0];
    uint32_t a2w = xe ? d[3] : d[1];
    float a0 = bfl(a01), a1 = bfh(a01), a2 = bfl(a2w);
    float b0 = bfl(d[2]), b1 = bfh(d[2]), b2 = bfl(d[3]);
    v0 = a0 + (b0 - a0)*wx;
    v1 = a1 + (b1 - a1)*wx;
    v2 = a2 + (b2 - a2)*wx;
}

// ---------------- unified prep: [0,g1b) g1-pack | [g1b,g1b+16) F | [g1b+16,g1b+31) W ----------------
__global__ __launch_bounds__(256)
void prep_all(const float* __restrict__ G1, const float* __restrict__ F,
              const float* __restrict__ W0, const float* __restrict__ W1,
              const float* __restrict__ W2, const float* __restrict__ Wc0,
              const float* __restrict__ Wc1, const float* __restrict__ Wc2,
              char* __restrict__ ws, int g1b){
    int bid = blockIdx.x, tid = threadIdx.x;
    if (bid < g1b){
        // pack G1 (3,256^3) f32 -> [z][y][x][4 bf16]; nontemporal reads so the
        // 192MB f32 stream doesn't evict the G1T pack we're writing into L3.
        int idx2 = (bid*256 + tid)*2;
        f32x2 a = __builtin_nontemporal_load((const f32x2*)(G1 + idx2));
        f32x2 b = __builtin_nontemporal_load((const f32x2*)(G1 + idx2 + 16777216));
        f32x2 c = __builtin_nontemporal_load((const f32x2*)(G1 + idx2 + 33554432));
        uint4 o = make_uint4(pack2(a[0], b[0]), pack2(c[0], 0.f),
                             pack2(a[1], b[1]), pack2(c[1], 0.f));
        *(uint4*)((uint32_t*)(ws + G1T_OFF) + idx2*2) = o;
        return;
    }
    if (bid < g1b + 16){
        // transpose F (32,16,16,16) -> bf16 [z][y][x][c]
        int idx = (bid - g1b)*256 + tid;
        uint32_t o[16];
        #pragma unroll
        for (int ch = 0; ch < 16; ch++){
            float a = F[(2*ch  )*4096 + idx];
            float b = F[(2*ch+1)*4096 + idx];
            o[ch] = pack2(a, b);
        }
        uint4* dst = (uint4*)(ws + FT_OFF);
        #pragma unroll
        for (int q = 0; q < 4; q++)
            dst[idx*4 + q] = make_uint4(o[q*4], o[q*4+1], o[q*4+2], o[q*4+3]);
        return;
    }
    // weights -> bf16 MFMA fragment layout
    // frag (kk,nt): lane l holds Wt[k = kk*32 + (l>>4)*8 + j][n = nt*16 + (l&15)], j=0..7.
    int gid = (bid - g1b - 16)*256 + tid;
    if (gid >= 58*64) return;
    int cg = gid >> 6, lane = gid & 63;
    const float* src; int K, N, base_cg, dstoff;
    if      (cg < 8)  { src = W0;  K = 32;  N = 128; base_cg = 0;  dstoff = W0_OFF; }
    else if (cg < 40) { src = W1;  K = 128; N = 128; base_cg = 8;  dstoff = W1_OFF; }
    else if (cg < 44) { src = W2;  K = 128; N = 16;  base_cg = 40; dstoff = W2_OFF; }
    else if (cg < 48) { src = Wc0; K = 31;  N = 64;  base_cg = 44; dstoff = C0_OFF; }
    else if (cg < 56) { src = Wc1; K = 64;  N = 64;  base_cg = 48; dstoff = C1_OFF; }
    else              { src = Wc2; K = 64;  N = 3;   base_cg = 56; dstoff = C2_OFF; }
    bool c0remap = (cg >= 44 && cg < 48);
    int local = cg - base_cg;
    int NT = (N + 15) >> 4;
    int nt = local % NT, kk = local / NT;
    int n = nt*16 + (lane & 15);
    int kbase = kk*32 + (lane >> 4)*8;
    uint32_t o[4];
    #pragma unroll
    for (int jj = 0; jj < 4; jj++){
        int k0 = kbase + jj*2, k1 = k0 + 1;
        int k0s = (c0remap && k0 > 16) ? k0 - 1 : k0;
        int k1s = (c0remap && k1 > 16) ? k1 - 1 : k1;
        bool v0 = (n < N) && (k0s < K) && !(c0remap && k0 == 16);
        bool v1 = (n < N) && (k1s < K) && !(c0remap && k1 == 16);
        float a = v0 ? src[k0s*N + n] : 0.f;
        float b = v1 ? src[k1s*N + n] : 0.f;
        o[jj] = pack2(a, b);
    }
    uint4* dst = (uint4*)(ws + dstoff);
    dst[local*64 + lane] = make_uint4(o[0], o[1], o[2], o[3]);
}

// ---------------- fused main: one BLOCK per ray, one WAVE per 64-sample half ----------------
// Dual-tile MLP: tiles (2t, 2t+1) computed together, weight frags shared -> 2x MFMA ILP.
template<bool G1PACK>
__global__ __launch_bounds__(128, 4)
void nerf_fused(const float* __restrict__ rays_o, const float* __restrict__ rays_d,
                const float* __restrict__ G1, const char* __restrict__ ws,
                float* __restrict__ out){
    __shared__ __align__(16) char smem[BLOCK_LDS];
    const int tid  = threadIdx.x;
    const int wv   = tid >> 6;
    const int lane = tid & 63;
    const int nl   = lane & 15;
    const int quad = lane >> 4;
    const int ray  = blockIdx.x;
    char*  FEB  = smem + wv*FE_BYTES;
    float* SIGf = (float*)(smem + SIG_OFF);
    float* COLf = (float*)(smem + COL_OFF);

    // ---- ray setup (uniform per block) ----
    float ox = rays_o[ray*3+0], oy = rays_o[ray*3+1], oz = rays_o[ray*3+2];
    float rx = rays_d[ray*3+0], ry = rays_d[ray*3+1], rz = rays_d[ray*3+2];
    float nrm = sqrtf(rx*rx + ry*ry + rz*rz);
    float dx = rx/nrm, dy = ry/nrm, dz = rz/nrm;
    float bq = ox*dx + oy*dy + oz*dz;
    float cq = ox*ox + oy*oy + oz*oz - RADIUS*RADIUS;
    float disc = bq*bq - cq;
    bool  hit = disc > 0.f;
    float sq   = sqrtf(hit ? disc : 1.f);
    float tmin = hit ? fmaxf(-bq - sq, 0.f) : 0.f;
    float tmax = hit ? (-bq + sq) : 0.f;

    // ---- SH enc of ray dir -> per-lane packed bf16 words (B-frag quads 0,1 of CIN) ----
    uint32_t encw0, encw1, encw2, encw3, cinmask;
    {
        float xx=dx*dx, yy=dy*dy, zz=dz*dz, xy=dx*dy, yz=dy*dz, xz=dx*dz;
        float sh0 = 0.28209479177387814f;
        float sh1 = -0.48860251190291987f*dy;
        float sh2 =  0.48860251190291987f*dz;
        float sh3 = -0.48860251190291987f*dx;
        float sh4 =  1.0925484305920792f*xy;
        float sh5 = -1.0925484305920792f*yz;
        float sh6 =  0.94617469575756f*zz - 0.31539156525252f;
        float sh7 = -1.0925484305920792f*xz;
        float sh8 =  0.5462742152960396f*(xx-yy);
        float sh9 =  0.5900435899266435f*dy*(-3.f*xx+yy);
        float sh10 = 2.890611442640554f*xy*dz;
        float sh11 = 0.4570457994644657f*dy*(1.f-5.f*zz);
        float sh12 = 0.3731763325901154f*dz*(5.f*zz-3.f);
        float sh13 = 0.4570457994644657f*dx*(1.f-5.f*zz);
        float sh14 = 1.445305721320277f*dz*(xx-yy);
        float sh15 = 0.5900435899266435f*dx*(-xx+3.f*yy);
        bool q0 = (quad == 0);
        encw0 = q0 ? pack2(sh0, sh1) : pack2(sh8,  sh9);
        encw1 = q0 ? pack2(sh2, sh3) : pack2(sh10, sh11);
        encw2 = q0 ? pack2(sh4, sh5) : pack2(sh12, sh13);
        encw3 = q0 ? pack2(sh6, sh7) : pack2(sh14, sh15);
        cinmask = (quad == 2) ? 0xFFFF0000u : 0xFFFFFFFFu;
    }

    const char* pW0 = ws + W0_OFF; const char* pW1 = ws + W1_OFF; const char* pW2 = ws + W2_OFF;
    const char* pC0 = ws + C0_OFF; const char* pC1 = ws + C1_OFF; const char* pC2 = ws + C2_OFF;
    const f32x4 vzero = {0.f, 0.f, 0.f, 0.f};

    #define RD_A(bp, linRow, m) \
        (*(const bf16x8*)((bp) + (linRow)*64 + ((quad ^ (((m)>>1)&3))*16)))
    #define LD_B(base, kk, NT, nt) \
        (*(const bf16x8*)((base) + (((kk)*(NT) + (nt))*64 + lane)*16))

    float Dn = (tmax - tmin) * (1.0f/STEP);
    int nv = (int)fminf(128.f, fmaxf(0.f, floorf(Dn + 0.5f) + 1.f));
    int rem = nv - wv*64;
    if (rem > 64) rem = 64;

    if (rem > 0){
        {   // ---- gather: lane gathers sample p = wv*64 + lane (if valid) ----
            if (lane < rem){
                int p = wv*64 + lane;
                float tmid = tmin + ((float)p + 0.5f) * STEP;
                float px = (ox + dx*tmid) * INV_RADIUS;
                float py = (oy + dy*tmid) * INV_RADIUS;
                float pz = (oz + dz*tmid) * INV_RADIUS;
                int x0,x1,y0,y1,z0,z1; float wx,wy,wz;
                toidx(px, 255.f, 256, x0, x1, wx);
                toidx(py, 255.f, 256, y0, y1, wy);
                toidx(pz, 255.f, 256, z0, z1, wz);
                float g1v[3];
                if constexpr (G1PACK){
                    const uint32_t* Gt = (const uint32_t*)(ws + G1T_OFF);
                    int xs = (x0 < 255) ? x0 : 254;
                    bool xe = (x0 == 255);
                    int r00 = (z0*256 + y0)*256 + xs, r01 = (z0*256 + y1)*256 + xs;
                    int r10 = (z1*256 + y0)*256 + xs, r11 = (z1*256 + y1)*256 + xs;
                    u32x4a d00 = *(const u32x4a*)(Gt + (size_t)r00*2);
                    u32x4a d01 = *(const u32x4a*)(Gt + (size_t)r01*2);
                    u32x4a d10 = *(const u32x4a*)(Gt + (size_t)r10*2);
                    u32x4a d11 = *(const u32x4a*)(Gt + (size_t)r11*2);
                    float v00x,v00y,v00z, v01x,v01y,v01z, v10x,v10y,v10z, v11x,v11y,v11z;
                    rowlerp(d00, xe, wx, v00x, v00y, v00z);
                    rowlerp(d01, xe, wx, v01x, v01y, v01z);
                    rowlerp(d10, xe, wx, v10x, v10y, v10z);
                    rowlerp(d11, xe, wx, v11x, v11y, v11z);
                    float c0x = v00x + (v01x - v00x)*wy, c1x = v10x + (v11x - v10x)*wy;
                    float c0y = v00y + (v01y - v00y)*wy, c1y = v10y + (v11y - v10y)*wy;
                    float c0z = v00z + (v01z - v00z)*wy, c1z = v10z + (v11z - v10z)*wy;
                    g1v[0] = c0x + (c1x - c0x)*wz;
                    g1v[1] = c0y + (c1y - c0y)*wz;
                    g1v[2] = c0z + (c1z - c0z)*wz;
                } else {
                    #pragma unroll
                    for (int ch = 0; ch < 3; ch++){
                        const float* gp = G1 + ch*16777216;
                        int b00 = (z0*256 + y0)*256, b01 = (z0*256 + y1)*256;
                        int b10 = (z1*256 + y0)*256, b11 = (z1*256 + y1)*256;
                        float c000 = gp[b00+x0], c001 = gp[b00+x1];
                        float c010 = gp[b01+x0], c011 = gp[b01+x1];
                        float c100 = gp[b10+x0], c101 = gp[b10+x1];
                        float c110 = gp[b11+x0], c111 = gp[b11+x1];
                        float c00 = c000 + (c001-c000)*wx;
                        float c01 = c010 + (c011-c010)*wx;
                        float c10 = c100 + (c101-c100)*wx;
                        float c11 = c110 + (c111-c110)*wx;
                        float c0 = c00 + (c01-c00)*wy;
                        float c1 = c10 + (c11-c10)*wy;
                        g1v[ch] = c0 + (c1-c0)*wz;
                    }
                }
                int fx0,fx1,fy0,fy1,fz0,fz1; float fwx,fwy,fwz;
                toidx(g1v[0], 15.f, 16, fx0, fx1, fwx);
                toidx(g1v[1], 15.f, 16, fy0, fy1, fwy);
                toidx(g1v[2], 15.f, 16, fz0, fz1, fwz);
                float feats[32];
                #pragma unroll
                for (int i = 0; i < 32; i++) feats[i] = 0.f;
                const uint4* Ft = (const uint4*)(ws + FT_OFF);
                #pragma unroll 2
                for (int corner = 0; corner < 8; corner++){
                    int cz = (corner>>2)&1, cy = (corner>>1)&1, cx = corner&1;
                    int xi = cx?fx1:fx0, yi = cy?fy1:fy0, zi = cz?fz1:fz0;
                    float w = (cx?fwx:1.f-fwx) * (cy?fwy:1.f-fwy) * (cz?fwz:1.f-fwz);
                    const uint4* cp = Ft + ((zi*16 + yi)*16 + xi)*4;
                    #pragma unroll
                    for (int q = 0; q < 4; q++){
                        uint4 v = cp[q];
                        uint32_t u[4] = {v.x, v.y, v.z, v.w};
                        #pragma unroll
                        for (int e = 0; e < 4; e++){
                            feats[q*8 + e*2    ] += w * __uint_as_float(u[e] << 16);
                            feats[q*8 + e*2 + 1] += w * __uint_as_float(u[e] & 0xFFFF0000u);
                        }
                    }
                }
                int fsw = (lane>>1)&3;
                #pragma unroll
                for (int c = 0; c < 4; c++){
                    uint4 v = make_uint4(pack2(feats[c*8+0], feats[c*8+1]),
                                         pack2(feats[c*8+2], feats[c*8+3]),
                                         pack2(feats[c*8+4], feats[c*8+5]),
                                         pack2(feats[c*8+6], feats[c*8+7]));
                    *(uint4*)(FEB + lane*64 + ((c^fsw)*16)) = v;
                }
            }
        }
        lds_fence();   // FE visible within wave

        int mtmax = (rem + 15) >> 4;
        // dual-tile loop: always compute the pair; garbage tiles masked at composite
        #pragma unroll 1
        for (int mp = 0; mp < mtmax; mp += 2){
            const int rA = mp*16 + nl;
            const int rB = rA + 16;
            const int tbA = wv*64 + mp*16;
            const int tbB = tbA + 16;

            // L0: W0^T(128x32) x feats(32x16) for both tiles, shared weight frags
            bf16x8 feA = RD_A(FEB, rA, rA);
            bf16x8 feB = RD_A(FEB, rB, rB);
            f32x4 a0A[8], a0B[8];
            PRIO1;
            #pragma unroll
            for (int nt = 0; nt < 8; nt++){
                bf16x8 w = LD_B(pW0, 0, 8, nt);
                a0A[nt] = __builtin_amdgcn_mfma_f32_16x16x32_bf16(w, feA, vzero, 0,0,0);
                a0B[nt] = __builtin_amdgcn_mfma_f32_16x16x32_bf16(w, feB, vzero, 0,0,0);
            }
            PRIO0;
            bf16x8 h1A[4], h1B[4];
            #pragma unroll
            for (int kk = 0; kk < 4; kk++){
                h1A[kk] = xpose4(a0A[2*kk], a0A[2*kk+1]);
                h1B[kk] = xpose4(a0B[2*kk], a0B[2*kk+1]);
            }

            // L1: 128x128
            f32x4 a1A[8], a1B[8];
            #pragma unroll
            for (int nt = 0; nt < 8; nt++){ a1A[nt] = vzero; a1B[nt] = vzero; }
            PRIO1;
            #pragma unroll
            for (int kk = 0; kk < 4; kk++)
                #pragma unroll
                for (int nt = 0; nt < 8; nt++){
                    bf16x8 w = LD_B(pW1, kk, 8, nt);
                    a1A[nt] = __builtin_amdgcn_mfma_f32_16x16x32_bf16(w, h1A[kk], a1A[nt], 0,0,0);
                    a1B[nt] = __builtin_amdgcn_mfma_f32_16x16x32_bf16(w, h1B[kk], a1B[nt], 0,0,0);
                }
            PRIO0;
            bf16x8 h2A[4], h2B[4];
            #pragma unroll
            for (int kk = 0; kk < 4; kk++){
                h2A[kk] = xpose4(a1A[2*kk], a1A[2*kk+1]);
                h2B[kk] = xpose4(a1B[2*kk], a1B[2*kk+1]);
            }

            // L2: sigma head 16x128 (no relu)
            f32x4 sA = vzero, sB = vzero;
            PRIO1;
            #pragma unroll
            for (int kk = 0; kk < 4; kk++){
                bf16x8 w = LD_B(pW2, kk, 1, 0);
                sA = __builtin_amdgcn_mfma_f32_16x16x32_bf16(w, h2A[kk], sA, 0,0,0);
                sB = __builtin_amdgcn_mfma_f32_16x16x32_bf16(w, h2B[kk], sB, 0,0,0);
            }
            PRIO0;
            if (quad == 0){ SIGf[tbA + nl] = sA[0]; SIGf[tbB + nl] = sB[0]; }

            // CIN B-frags: quads 0,1 = SH enc; quads 2,3 = sig_out[1:16] (pad k=16)
            bf16x8 cinA, cinB;
            {
                uint32_t ca = cvtpk(sA[0], sA[1]);
                uint32_t cb = cvtpk(sA[2], sA[3]);
                p32swap(ca, cb); p16swap(ca, cb);
                uint32_t cw0 = encw0, cw2 = encw2;
                p32swap(cw0, ca);
                p32swap(cw2, cb);
                cw0 &= cinmask;
                uint32_t cw1 = (quad < 2) ? encw1 : ca;
                uint32_t cw3 = (quad < 2) ? encw3 : cb;
                cinA = frag_from(cw0, cw1, cw2, cw3);
            }
            {
                uint32_t ca = cvtpk(sB[0], sB[1]);
                uint32_t cb = cvtpk(sB[2], sB[3]);
                p32swap(ca, cb); p16swap(ca, cb);
                uint32_t cw0 = encw0, cw2 = encw2;
                p32swap(cw0, ca);
                p32swap(cw2, cb);
                cw0 &= cinmask;
                uint32_t cw1 = (quad < 2) ? encw1 : ca;
                uint32_t cw3 = (quad < 2) ? encw3 : cb;
                cinB = frag_from(cw0, cw1, cw2, cw3);
            }

            // C0: 64x32
            f32x4 c0A[4], c0B[4];
            PRIO1;
            #pragma unroll
            for (int nt = 0; nt < 4; nt++){
                bf16x8 w = LD_B(pC0, 0, 4, nt);
                c0A[nt] = __builtin_amdgcn_mfma_f32_16x16x32_bf16(w, cinA, vzero, 0,0,0);
                c0B[nt] = __builtin_amdgcn_mfma_f32_16x16x32_bf16(w, cinB, vzero, 0,0,0);
            }
            PRIO0;
            bf16x8 g1A[2], g1B[2];
            #pragma unroll
            for (int kk = 0; kk < 2; kk++){
                g1A[kk] = xpose4(c0A[2*kk], c0A[2*kk+1]);
                g1B[kk] = xpose4(c0B[2*kk], c0B[2*kk+1]);
            }

            // C1: 64x64
            f32x4 c1A[4], c1B[4];
            #pragma unroll
            for (int nt = 0; nt < 4; nt++){ c1A[nt] = vzero; c1B[nt] = vzero; }
            PRIO1;
            #pragma unroll
            for (int kk = 0; kk < 2; kk++)
                #pragma unroll
                for (int nt = 0; nt < 4; nt++){
                    bf16x8 w = LD_B(pC1, kk, 4, nt);
                    c1A[nt] = __builtin_amdgcn_mfma_f32_16x16x32_bf16(w, g1A[kk], c1A[nt], 0,0,0);
                    c1B[nt] = __builtin_amdgcn_mfma_f32_16x16x32_bf16(w, g1B[kk], c1B[nt], 0,0,0);
                }
            PRIO0;
            bf16x8 g2A[2], g2B[2];
            #pragma unroll
            for (int kk = 0; kk < 2; kk++){
                g2A[kk] = xpose4(c1A[2*kk], c1A[2*kk+1]);
                g2B[kk] = xpose4(c1B[2*kk], c1B[2*kk+1]);
            }

            // C2: color head (no relu); rows 0..2 = r,g,b on quad0
            f32x4 ccA = vzero, ccB = vzero;
            PRIO1;
            #pragma unroll
            for (int kk = 0; kk < 2; kk++){
                bf16x8 w = LD_B(pC2, kk, 1, 0);
                ccA = __builtin_amdgcn_mfma_f32_16x16x32_bf16(w, g2A[kk], ccA, 0,0,0);
                ccB = __builtin_amdgcn_mfma_f32_16x16x32_bf16(w, g2B[kk], ccB, 0,0,0);
            }
            PRIO0;
            if (quad == 0){
                *(float2*)(COLf + (tbA + nl)*4) = make_float2(ccA[0], ccA[1]);
                COLf[(tbA + nl)*4 + 2] = ccA[2];
                *(float2*)(COLf + (tbB + nl)*4) = make_float2(ccB[0], ccB[1]);
                COLf[(tbB + nl)*4 + 2] = ccB[2];
            }
        }
    }

    __syncthreads();

    if (wv != 0) return;

    // ---- composite: wave 0 scans all 128 samples (2 per lane) ----
    float t0 = tmin + ((float)lane + 0.5f) * STEP;
    float t1 = tmin + ((float)(lane + 64) + 0.5f) * STEP;
    bool  m0 = hit && (t0 <= tmax);
    bool  m1 = hit && (t1 <= tmax);
    float sig0 = m0 ? fmaxf(SIGf[lane], 0.f) : 0.f;
    float sig1 = m1 ? fmaxf(SIGf[lane + 64], 0.f) : 0.f;
    float e0 = expf(-sig0 * STEP), e1 = expf(-sig1 * STEP);
    float al0 = 1.f - e0, al1 = 1.f - e1;
    float li0 = logf(e0 + 1e-10f), li1 = logf(e1 + 1e-10f);
    float incl0 = li0, incl1 = li1;
    #pragma unroll
    for (int off = 1; off < 64; off <<= 1){
        float v0 = __shfl_up(incl0, off);
        float v1 = __shfl_up(incl1, off);
        if (lane >= off){ incl0 += v0; incl1 += v1; }
    }
    float tot0 = __shfl(incl0, 63);
    float ex0 = incl0 - li0;
    float ex1 = tot0 + incl1 - li1;
    float w0 = al0 * expf(ex0);
    float w1 = al1 * expf(ex1);
    float cr0 = m0 ? COLf[lane*4+0] : 0.f;
    float cg0 = m0 ? COLf[lane*4+1] : 0.f;
    float cb0 = m0 ? COLf[lane*4+2] : 0.f;
    float cr1 = m1 ? COLf[(lane+64)*4+0] : 0.f;
    float cg1 = m1 ? COLf[(lane+64)*4+1] : 0.f;
    float cb1 = m1 ? COLf[(lane+64)*4+2] : 0.f;
    float r = w0 / (1.f + expf(-cr0)) + w1 / (1.f + expf(-cr1));
    float g = w0 / (1.f + expf(-cg0)) + w1 / (1.f + expf(-cg1));
    float b = w0 / (1.f + expf(-cb0)) + w1 / (1.f + expf(-cb1));
    float wa = w0 + w1;
    #pragma unroll
    for (int off = 32; off > 0; off >>= 1){
        r  += __shfl_xor(r,  off);
        g  += __shfl_xor(g,  off);
        b  += __shfl_xor(b,  off);
        wa += __shfl_xor(wa, off);
    }
    if (lane == 0){
        out[ray*3+0] = r + (1.f - wa);
        out[ray*3+1] = g + (1.f - wa);
        out[ray*3+2] = b + (1.f - wa);
    }
    #undef RD_A
    #undef LD_B
}

extern "C" void kernel_launch(void* const* d_in, const int* in_sizes, int n_in,
                              void* d_out, int out_size, void* d_ws, size_t ws_size,
                              hipStream_t stream){
    const float* rays_o = (const float*)d_in[0];
    const float* rays_d = (const float*)d_in[1];
    const float* G1     = (const float*)d_in[2];
    const float* F      = (const float*)d_in[3];
    bool fast = (ws_size >= WS_NEED);
    int g1b = fast ? 32768 : 0;
    prep_all<<<g1b + 31, 256, 0, stream>>>(G1, F,
                                           (const float*)d_in[4], (const float*)d_in[5],
                                           (const float*)d_in[6], (const float*)d_in[7],
                                           (const float*)d_in[8], (const float*)d_in[9],
                                           (char*)d_ws, g1b);
    if (fast)
        nerf_fused<true><<<4096, 128, 0, stream>>>(rays_o, rays_d, G1, (const char*)d_ws, (float*)d_out);
    else
        nerf_fused<false><<<4096, 128, 0, stream>>>(rays_o, rays_d, G1, (const char*)d_ws, (float*)d_out);
}

// Round 6
// 412.816 us; speedup vs baseline: 1.0605x; 1.0605x over previous
//
#include <hip/hip_runtime.h>
#include <stdint.h>

#define STEP 0.02f
#define INV_RADIUS (1.0f/1.3f)
#define RADIUS 1.3f

typedef __bf16   bf16x8 __attribute__((ext_vector_type(8)));
typedef float    f32x4  __attribute__((ext_vector_type(4)));
typedef float    f32x2  __attribute__((ext_vector_type(2)));
typedef uint32_t u32x4  __attribute__((ext_vector_type(4)));
typedef uint32_t u32x4a __attribute__((ext_vector_type(4), aligned(8)));

// ---------------- ws layout (bytes) ----------------
#define FT_OFF   0         // F transposed bf16 [z16][y16][x16][c32] = 262144 B
#define W0_OFF   262144    // sig W0  K=32  N=128 : 1kk x 8nt  = 8192 B
#define W1_OFF   270336    // sig W1  K=128 N=128 : 4kk x 8nt  = 32768 B
#define W2_OFF   303104    // sig W2  K=128 N=16  : 4kk x 1nt  = 4096 B
#define C0_OFF   307200    // col W0  K=31->32 (pad at k=16) N=64 : 1x4 = 4096 B
#define C1_OFF   311296    // col W1  K=64 N=64 : 2x4          = 8192 B
#define C2_OFF   319488    // col W2  K=64 N=3->16 : 2x1       = 2048 B (end 321536)
// packed G1: [z][y][x][ch0,ch1,ch2,pad] bf16 = 8 B/cell, 256^3 cells
#define G1T_OFF  321536
#define WS_NEED  (321536ull + 134217728ull)

// ---------------- block LDS (bytes) ----------------
#define FE_BYTES  4096     // per wave: 64 rows x 64B
#define SIG_OFF   8192     // 128 f32 = 512
#define COL_OFF   8704     // 128 x 4 f32 = 2048
#define BLOCK_LDS 10752

#define PRIO1 __builtin_amdgcn_s_setprio(1)
#define PRIO0 __builtin_amdgcn_s_setprio(0)

__device__ __forceinline__ uint32_t pack2(float a, float b){
    uint32_t ua = __float_as_uint(a); ua += 0x7FFFu + ((ua>>16)&1u);
    uint32_t ub = __float_as_uint(b); ub += 0x7FFFu + ((ub>>16)&1u);
    return (ua>>16) | (ub & 0xFFFF0000u);
}
__device__ __forceinline__ float bfl(uint32_t u){ return __uint_as_float(u << 16); }
__device__ __forceinline__ float bfh(uint32_t u){ return __uint_as_float(u & 0xFFFF0000u); }
__device__ __forceinline__ void toidx(float c, float sizem1, int isize,
                                      int& i0, int& i1, float& w){
    float t = (c + 1.f) * 0.5f * sizem1;
    t = fminf(fmaxf(t, 0.f), sizem1);
    float f = floorf(t);
    i0 = (int)f;
    i1 = i0 + 1; if (i1 > isize - 1) i1 = isize - 1;
    w = t - f;
}
__device__ __forceinline__ void lds_fence(){
    asm volatile("s_waitcnt lgkmcnt(0)" ::: "memory");
}
__device__ __forceinline__ uint32_t cvtpk(float lo, float hi){
    uint32_t r;
    asm("v_cvt_pk_bf16_f32 %0, %1, %2" : "=v"(r) : "v"(lo), "v"(hi));
    return r;
}
__device__ __forceinline__ void p32swap(uint32_t& a, uint32_t& b){
    asm("v_permlane32_swap_b32 %0, %1" : "+v"(a), "+v"(b));
}
__device__ __forceinline__ void p16swap(uint32_t& a, uint32_t& b){
    asm("v_permlane16_swap_b32 %0, %1" : "+v"(a), "+v"(b));
}
__device__ __forceinline__ uint32_t pkrelu(float a, float b){
    return cvtpk(fmaxf(a, 0.f), fmaxf(b, 0.f));
}
__device__ __forceinline__ bf16x8 frag_from(uint32_t a, uint32_t b, uint32_t c, uint32_t d){
    union { u32x4 u; bf16x8 h; } cv;
    cv.u = (u32x4){a, b, c, d};
    return cv.h;
}
// D-tiles -> next-layer B-frag in-register transpose (+relu)
__device__ __forceinline__ bf16x8 xpose4(const f32x4& t0, const f32x4& t1){
    uint32_t A = pkrelu(t0[0], t0[1]);
    uint32_t B = pkrelu(t0[2], t0[3]);
    uint32_t C = pkrelu(t1[0], t1[1]);
    uint32_t D = pkrelu(t1[2], t1[3]);
    p32swap(A, C); p16swap(A, C);
    p32swap(B, D); p16swap(B, D);
    return frag_from(A, B, C, D);
}
// x-lerp of one packed (z,y)-row: cells A(dwords 0,1) B(dwords 2,3); xe => x0==255
__device__ __forceinline__ void rowlerp(const u32x4a d, bool xe, float wx,
                                        float& v0, float& v1, float& v2){
    uint32_t a01 = xe ? d[2] : d[0];
    uint32_t a2w = xe ? d[3] : d[1];
    float a0 = bfl(a01), a1 = bfh(a01), a2 = bfl(a2w);
    float b0 = bfl(d[2]), b1 = bfh(d[2]), b2 = bfl(d[3]);
    v0 = a0 + (b0 - a0)*wx;
    v1 = a1 + (b1 - a1)*wx;
    v2 = a2 + (b2 - a2)*wx;
}

// ---------------- unified prep: [0,g1b) g1-pack | [g1b,g1b+16) F | [g1b+16,g1b+31) W ----------------
__global__ __launch_bounds__(256)
void prep_all(const float* __restrict__ G1, const float* __restrict__ F,
              const float* __restrict__ W0, const float* __restrict__ W1,
              const float* __restrict__ W2, const float* __restrict__ Wc0,
              const float* __restrict__ Wc1, const float* __restrict__ Wc2,
              char* __restrict__ ws, int g1b){
    int bid = blockIdx.x, tid = threadIdx.x;
    if (bid < g1b){
        // pack G1 (3,256^3) f32 -> [z][y][x][4 bf16]; nontemporal reads so the
        // 192MB f32 stream doesn't evict the G1T pack we're writing into L3.
        int idx2 = (bid*256 + tid)*2;
        f32x2 a = __builtin_nontemporal_load((const f32x2*)(G1 + idx2));
        f32x2 b = __builtin_nontemporal_load((const f32x2*)(G1 + idx2 + 16777216));
        f32x2 c = __builtin_nontemporal_load((const f32x2*)(G1 + idx2 + 33554432));
        uint4 o = make_uint4(pack2(a[0], b[0]), pack2(c[0], 0.f),
                             pack2(a[1], b[1]), pack2(c[1], 0.f));
        *(uint4*)((uint32_t*)(ws + G1T_OFF) + idx2*2) = o;
        return;
    }
    if (bid < g1b + 16){
        // transpose F (32,16,16,16) -> bf16 [z][y][x][c]
        int idx = (bid - g1b)*256 + tid;
        uint32_t o[16];
        #pragma unroll
        for (int ch = 0; ch < 16; ch++){
            float a = F[(2*ch  )*4096 + idx];
            float b = F[(2*ch+1)*4096 + idx];
            o[ch] = pack2(a, b);
        }
        uint4* dst = (uint4*)(ws + FT_OFF);
        #pragma unroll
        for (int q = 0; q < 4; q++)
            dst[idx*4 + q] = make_uint4(o[q*4], o[q*4+1], o[q*4+2], o[q*4+3]);
        return;
    }
    // weights -> bf16 MFMA fragment layout
    // frag (kk,nt): lane l holds Wt[k = kk*32 + (l>>4)*8 + j][n = nt*16 + (l&15)], j=0..7.
    int gid = (bid - g1b - 16)*256 + tid;
    if (gid >= 58*64) return;
    int cg = gid >> 6, lane = gid & 63;
    const float* src; int K, N, base_cg, dstoff;
    if      (cg < 8)  { src = W0;  K = 32;  N = 128; base_cg = 0;  dstoff = W0_OFF; }
    else if (cg < 40) { src = W1;  K = 128; N = 128; base_cg = 8;  dstoff = W1_OFF; }
    else if (cg < 44) { src = W2;  K = 128; N = 16;  base_cg = 40; dstoff = W2_OFF; }
    else if (cg < 48) { src = Wc0; K = 31;  N = 64;  base_cg = 44; dstoff = C0_OFF; }
    else if (cg < 56) { src = Wc1; K = 64;  N = 64;  base_cg = 48; dstoff = C1_OFF; }
    else              { src = Wc2; K = 64;  N = 3;   base_cg = 56; dstoff = C2_OFF; }
    bool c0remap = (cg >= 44 && cg < 48);
    int local = cg - base_cg;
    int NT = (N + 15) >> 4;
    int nt = local % NT, kk = local / NT;
    int n = nt*16 + (lane & 15);
    int kbase = kk*32 + (lane >> 4)*8;
    uint32_t o[4];
    #pragma unroll
    for (int jj = 0; jj < 4; jj++){
        int k0 = kbase + jj*2, k1 = k0 + 1;
        int k0s = (c0remap && k0 > 16) ? k0 - 1 : k0;
        int k1s = (c0remap && k1 > 16) ? k1 - 1 : k1;
        bool v0 = (n < N) && (k0s < K) && !(c0remap && k0 == 16);
        bool v1 = (n < N) && (k1s < K) && !(c0remap && k1 == 16);
        float a = v0 ? src[k0s*N + n] : 0.f;
        float b = v1 ? src[k1s*N + n] : 0.f;
        o[jj] = pack2(a, b);
    }
    uint4* dst = (uint4*)(ws + dstoff);
    dst[local*64 + lane] = make_uint4(o[0], o[1], o[2], o[3]);
}

// ---------------- fused main: one BLOCK per ray, one WAVE per 64-sample half ----------------
// Dual-tile MLP with fused L0/C0 xpose (peak ~150 VGPR); (128,3) => cap ~170, no spill.
template<bool G1PACK>
__global__ __launch_bounds__(128, 3)
void nerf_fused(const float* __restrict__ rays_o, const float* __restrict__ rays_d,
                const float* __restrict__ G1, const char* __restrict__ ws,
                float* __restrict__ out){
    __shared__ __align__(16) char smem[BLOCK_LDS];
    const int tid  = threadIdx.x;
    const int wv   = tid >> 6;
    const int lane = tid & 63;
    const int nl   = lane & 15;
    const int quad = lane >> 4;
    const int ray  = blockIdx.x;
    char*  FEB  = smem + wv*FE_BYTES;
    float* SIGf = (float*)(smem + SIG_OFF);
    float* COLf = (float*)(smem + COL_OFF);

    // ---- ray setup (uniform per block) ----
    float ox = rays_o[ray*3+0], oy = rays_o[ray*3+1], oz = rays_o[ray*3+2];
    float rx = rays_d[ray*3+0], ry = rays_d[ray*3+1], rz = rays_d[ray*3+2];
    float nrm = sqrtf(rx*rx + ry*ry + rz*rz);
    float dx = rx/nrm, dy = ry/nrm, dz = rz/nrm;
    float bq = ox*dx + oy*dy + oz*dz;
    float cq = ox*ox + oy*oy + oz*oz - RADIUS*RADIUS;
    float disc = bq*bq - cq;
    bool  hit = disc > 0.f;
    float sq   = sqrtf(hit ? disc : 1.f);
    float tmin = hit ? fmaxf(-bq - sq, 0.f) : 0.f;
    float tmax = hit ? (-bq + sq) : 0.f;

    // ---- SH enc of ray dir -> per-lane packed bf16 words (B-frag quads 0,1 of CIN) ----
    uint32_t encw0, encw1, encw2, encw3, cinmask;
    {
        float xx=dx*dx, yy=dy*dy, zz=dz*dz, xy=dx*dy, yz=dy*dz, xz=dx*dz;
        float sh0 = 0.28209479177387814f;
        float sh1 = -0.48860251190291987f*dy;
        float sh2 =  0.48860251190291987f*dz;
        float sh3 = -0.48860251190291987f*dx;
        float sh4 =  1.0925484305920792f*xy;
        float sh5 = -1.0925484305920792f*yz;
        float sh6 =  0.94617469575756f*zz - 0.31539156525252f;
        float sh7 = -1.0925484305920792f*xz;
        float sh8 =  0.5462742152960396f*(xx-yy);
        float sh9 =  0.5900435899266435f*dy*(-3.f*xx+yy);
        float sh10 = 2.890611442640554f*xy*dz;
        float sh11 = 0.4570457994644657f*dy*(1.f-5.f*zz);
        float sh12 = 0.3731763325901154f*dz*(5.f*zz-3.f);
        float sh13 = 0.4570457994644657f*dx*(1.f-5.f*zz);
        float sh14 = 1.445305721320277f*dz*(xx-yy);
        float sh15 = 0.5900435899266435f*dx*(-xx+3.f*yy);
        bool q0 = (quad == 0);
        encw0 = q0 ? pack2(sh0, sh1) : pack2(sh8,  sh9);
        encw1 = q0 ? pack2(sh2, sh3) : pack2(sh10, sh11);
        encw2 = q0 ? pack2(sh4, sh5) : pack2(sh12, sh13);
        encw3 = q0 ? pack2(sh6, sh7) : pack2(sh14, sh15);
        cinmask = (quad == 2) ? 0xFFFF0000u : 0xFFFFFFFFu;
    }

    const char* pW0 = ws + W0_OFF; const char* pW1 = ws + W1_OFF; const char* pW2 = ws + W2_OFF;
    const char* pC0 = ws + C0_OFF; const char* pC1 = ws + C1_OFF; const char* pC2 = ws + C2_OFF;
    const f32x4 vzero = {0.f, 0.f, 0.f, 0.f};

    #define RD_A(bp, linRow, m) \
        (*(const bf16x8*)((bp) + (linRow)*64 + ((quad ^ (((m)>>1)&3))*16)))
    #define LD_B(base, kk, NT, nt) \
        (*(const bf16x8*)((base) + (((kk)*(NT) + (nt))*64 + lane)*16))

    float Dn = (tmax - tmin) * (1.0f/STEP);
    int nv = (int)fminf(128.f, fmaxf(0.f, floorf(Dn + 0.5f) + 1.f));
    int rem = nv - wv*64;
    if (rem > 64) rem = 64;

    if (rem > 0){
        {   // ---- gather: lane gathers sample p = wv*64 + lane (if valid) ----
            if (lane < rem){
                int p = wv*64 + lane;
                float tmid = tmin + ((float)p + 0.5f) * STEP;
                float px = (ox + dx*tmid) * INV_RADIUS;
                float py = (oy + dy*tmid) * INV_RADIUS;
                float pz = (oz + dz*tmid) * INV_RADIUS;
                int x0,x1,y0,y1,z0,z1; float wx,wy,wz;
                toidx(px, 255.f, 256, x0, x1, wx);
                toidx(py, 255.f, 256, y0, y1, wy);
                toidx(pz, 255.f, 256, z0, z1, wz);
                float g1v[3];
                if constexpr (G1PACK){
                    const uint32_t* Gt = (const uint32_t*)(ws + G1T_OFF);
                    int xs = (x0 < 255) ? x0 : 254;
                    bool xe = (x0 == 255);
                    int r00 = (z0*256 + y0)*256 + xs, r01 = (z0*256 + y1)*256 + xs;
                    int r10 = (z1*256 + y0)*256 + xs, r11 = (z1*256 + y1)*256 + xs;
                    u32x4a d00 = *(const u32x4a*)(Gt + (size_t)r00*2);
                    u32x4a d01 = *(const u32x4a*)(Gt + (size_t)r01*2);
                    u32x4a d10 = *(const u32x4a*)(Gt + (size_t)r10*2);
                    u32x4a d11 = *(const u32x4a*)(Gt + (size_t)r11*2);
                    float v00x,v00y,v00z, v01x,v01y,v01z, v10x,v10y,v10z, v11x,v11y,v11z;
                    rowlerp(d00, xe, wx, v00x, v00y, v00z);
                    rowlerp(d01, xe, wx, v01x, v01y, v01z);
                    rowlerp(d10, xe, wx, v10x, v10y, v10z);
                    rowlerp(d11, xe, wx, v11x, v11y, v11z);
                    float c0x = v00x + (v01x - v00x)*wy, c1x = v10x + (v11x - v10x)*wy;
                    float c0y = v00y + (v01y - v00y)*wy, c1y = v10y + (v11y - v10y)*wy;
                    float c0z = v00z + (v01z - v00z)*wy, c1z = v10z + (v11z - v10z)*wy;
                    g1v[0] = c0x + (c1x - c0x)*wz;
                    g1v[1] = c0y + (c1y - c0y)*wz;
                    g1v[2] = c0z + (c1z - c0z)*wz;
                } else {
                    #pragma unroll
                    for (int ch = 0; ch < 3; ch++){
                        const float* gp = G1 + ch*16777216;
                        int b00 = (z0*256 + y0)*256, b01 = (z0*256 + y1)*256;
                        int b10 = (z1*256 + y0)*256, b11 = (z1*256 + y1)*256;
                        float c000 = gp[b00+x0], c001 = gp[b00+x1];
                        float c010 = gp[b01+x0], c011 = gp[b01+x1];
                        float c100 = gp[b10+x0], c101 = gp[b10+x1];
                        float c110 = gp[b11+x0], c111 = gp[b11+x1];
                        float c00 = c000 + (c001-c000)*wx;
                        float c01 = c010 + (c011-c010)*wx;
                        float c10 = c100 + (c101-c100)*wx;
                        float c11 = c110 + (c111-c110)*wx;
                        float c0 = c00 + (c01-c00)*wy;
                        float c1 = c10 + (c11-c10)*wy;
                        g1v[ch] = c0 + (c1-c0)*wz;
                    }
                }
                int fx0,fx1,fy0,fy1,fz0,fz1; float fwx,fwy,fwz;
                toidx(g1v[0], 15.f, 16, fx0, fx1, fwx);
                toidx(g1v[1], 15.f, 16, fy0, fy1, fwy);
                toidx(g1v[2], 15.f, 16, fz0, fz1, fwz);
                float feats[32];
                #pragma unroll
                for (int i = 0; i < 32; i++) feats[i] = 0.f;
                const uint4* Ft = (const uint4*)(ws + FT_OFF);
                #pragma unroll 2
                for (int corner = 0; corner < 8; corner++){
                    int cz = (corner>>2)&1, cy = (corner>>1)&1, cx = corner&1;
                    int xi = cx?fx1:fx0, yi = cy?fy1:fy0, zi = cz?fz1:fz0;
                    float w = (cx?fwx:1.f-fwx) * (cy?fwy:1.f-fwy) * (cz?fwz:1.f-fwz);
                    const uint4* cp = Ft + ((zi*16 + yi)*16 + xi)*4;
                    #pragma unroll
                    for (int q = 0; q < 4; q++){
                        uint4 v = cp[q];
                        uint32_t u[4] = {v.x, v.y, v.z, v.w};
                        #pragma unroll
                        for (int e = 0; e < 4; e++){
                            feats[q*8 + e*2    ] += w * __uint_as_float(u[e] << 16);
                            feats[q*8 + e*2 + 1] += w * __uint_as_float(u[e] & 0xFFFF0000u);
                        }
                    }
                }
                int fsw = (lane>>1)&3;
                #pragma unroll
                for (int c = 0; c < 4; c++){
                    uint4 v = make_uint4(pack2(feats[c*8+0], feats[c*8+1]),
                                         pack2(feats[c*8+2], feats[c*8+3]),
                                         pack2(feats[c*8+4], feats[c*8+5]),
                                         pack2(feats[c*8+6], feats[c*8+7]));
                    *(uint4*)(FEB + lane*64 + ((c^fsw)*16)) = v;
                }
            }
        }
        lds_fence();   // FE visible within wave

        int mtmax = (rem + 15) >> 4;
        // dual-tile loop: always compute the pair; garbage tiles masked at composite
        #pragma unroll 1
        for (int mp = 0; mp < mtmax; mp += 2){
            const int rA = mp*16 + nl;
            const int rB = rA + 16;
            const int tbA = wv*64 + mp*16;
            const int tbB = tbA + 16;

            // L0: W0^T(128x32) x feats(32x16), xpose fused per-kk (keeps peak regs low)
            bf16x8 feA = RD_A(FEB, rA, rA);
            bf16x8 feB = RD_A(FEB, rB, rB);
            bf16x8 h1A[4], h1B[4];
            #pragma unroll
            for (int kk = 0; kk < 4; kk++){
                bf16x8 w0a = LD_B(pW0, 0, 8, 2*kk);
                bf16x8 w0b = LD_B(pW0, 0, 8, 2*kk+1);
                PRIO1;
                f32x4 tA0 = __builtin_amdgcn_mfma_f32_16x16x32_bf16(w0a, feA, vzero, 0,0,0);
                f32x4 tB0 = __builtin_amdgcn_mfma_f32_16x16x32_bf16(w0a, feB, vzero, 0,0,0);
                f32x4 tA1 = __builtin_amdgcn_mfma_f32_16x16x32_bf16(w0b, feA, vzero, 0,0,0);
                f32x4 tB1 = __builtin_amdgcn_mfma_f32_16x16x32_bf16(w0b, feB, vzero, 0,0,0);
                PRIO0;
                h1A[kk] = xpose4(tA0, tA1);
                h1B[kk] = xpose4(tB0, tB1);
            }

            // L1: 128x128
            f32x4 a1A[8], a1B[8];
            #pragma unroll
            for (int nt = 0; nt < 8; nt++){ a1A[nt] = vzero; a1B[nt] = vzero; }
            PRIO1;
            #pragma unroll
            for (int kk = 0; kk < 4; kk++)
                #pragma unroll
                for (int nt = 0; nt < 8; nt++){
                    bf16x8 w = LD_B(pW1, kk, 8, nt);
                    a1A[nt] = __builtin_amdgcn_mfma_f32_16x16x32_bf16(w, h1A[kk], a1A[nt], 0,0,0);
                    a1B[nt] = __builtin_amdgcn_mfma_f32_16x16x32_bf16(w, h1B[kk], a1B[nt], 0,0,0);
                }
            PRIO0;
            bf16x8 h2A[4], h2B[4];
            #pragma unroll
            for (int kk = 0; kk < 4; kk++){
                h2A[kk] = xpose4(a1A[2*kk], a1A[2*kk+1]);
                h2B[kk] = xpose4(a1B[2*kk], a1B[2*kk+1]);
            }

            // L2: sigma head 16x128 (no relu)
            f32x4 sA = vzero, sB = vzero;
            PRIO1;
            #pragma unroll
            for (int kk = 0; kk < 4; kk++){
                bf16x8 w = LD_B(pW2, kk, 1, 0);
                sA = __builtin_amdgcn_mfma_f32_16x16x32_bf16(w, h2A[kk], sA, 0,0,0);
                sB = __builtin_amdgcn_mfma_f32_16x16x32_bf16(w, h2B[kk], sB, 0,0,0);
            }
            PRIO0;
            if (quad == 0){ SIGf[tbA + nl] = sA[0]; SIGf[tbB + nl] = sB[0]; }

            // CIN B-frags: quads 0,1 = SH enc; quads 2,3 = sig_out[1:16] (pad k=16)
            bf16x8 cinA, cinB;
            {
                uint32_t ca = cvtpk(sA[0], sA[1]);
                uint32_t cb = cvtpk(sA[2], sA[3]);
                p32swap(ca, cb); p16swap(ca, cb);
                uint32_t cw0 = encw0, cw2 = encw2;
                p32swap(cw0, ca);
                p32swap(cw2, cb);
                cw0 &= cinmask;
                uint32_t cw1 = (quad < 2) ? encw1 : ca;
                uint32_t cw3 = (quad < 2) ? encw3 : cb;
                cinA = frag_from(cw0, cw1, cw2, cw3);
            }
            {
                uint32_t ca = cvtpk(sB[0], sB[1]);
                uint32_t cb = cvtpk(sB[2], sB[3]);
                p32swap(ca, cb); p16swap(ca, cb);
                uint32_t cw0 = encw0, cw2 = encw2;
                p32swap(cw0, ca);
                p32swap(cw2, cb);
                cw0 &= cinmask;
                uint32_t cw1 = (quad < 2) ? encw1 : ca;
                uint32_t cw3 = (quad < 2) ? encw3 : cb;
                cinB = frag_from(cw0, cw1, cw2, cw3);
            }

            // C0: 64x32, xpose fused per-kk
            bf16x8 g1A[2], g1B[2];
            #pragma unroll
            for (int kk = 0; kk < 2; kk++){
                bf16x8 wa = LD_B(pC0, 0, 4, 2*kk);
                bf16x8 wb = LD_B(pC0, 0, 4, 2*kk+1);
                PRIO1;
                f32x4 tA0 = __builtin_amdgcn_mfma_f32_16x16x32_bf16(wa, cinA, vzero, 0,0,0);
                f32x4 tB0 = __builtin_amdgcn_mfma_f32_16x16x32_bf16(wa, cinB, vzero, 0,0,0);
                f32x4 tA1 = __builtin_amdgcn_mfma_f32_16x16x32_bf16(wb, cinA, vzero, 0,0,0);
                f32x4 tB1 = __builtin_amdgcn_mfma_f32_16x16x32_bf16(wb, cinB, vzero, 0,0,0);
                PRIO0;
                g1A[kk] = xpose4(tA0, tA1);
                g1B[kk] = xpose4(tB0, tB1);
            }

            // C1: 64x64
            f32x4 c1A[4], c1B[4];
            #pragma unroll
            for (int nt = 0; nt < 4; nt++){ c1A[nt] = vzero; c1B[nt] = vzero; }
            PRIO1;
            #pragma unroll
            for (int kk = 0; kk < 2; kk++)
                #pragma unroll
                for (int nt = 0; nt < 4; nt++){
                    bf16x8 w = LD_B(pC1, kk, 4, nt);
                    c1A[nt] = __builtin_amdgcn_mfma_f32_16x16x32_bf16(w, g1A[kk], c1A[nt], 0,0,0);
                    c1B[nt] = __builtin_amdgcn_mfma_f32_16x16x32_bf16(w, g1B[kk], c1B[nt], 0,0,0);
                }
            PRIO0;
            bf16x8 g2A[2], g2B[2];
            #pragma unroll
            for (int kk = 0; kk < 2; kk++){
                g2A[kk] = xpose4(c1A[2*kk], c1A[2*kk+1]);
                g2B[kk] = xpose4(c1B[2*kk], c1B[2*kk+1]);
            }

            // C2: color head (no relu); rows 0..2 = r,g,b on quad0
            f32x4 ccA = vzero, ccB = vzero;
            PRIO1;
            #pragma unroll
            for (int kk = 0; kk < 2; kk++){
                bf16x8 w = LD_B(pC2, kk, 1, 0);
                ccA = __builtin_amdgcn_mfma_f32_16x16x32_bf16(w, g2A[kk], ccA, 0,0,0);
                ccB = __builtin_amdgcn_mfma_f32_16x16x32_bf16(w, g2B[kk], ccB, 0,0,0);
            }
            PRIO0;
            if (quad == 0){
                *(float2*)(COLf + (tbA + nl)*4) = make_float2(ccA[0], ccA[1]);
                COLf[(tbA + nl)*4 + 2] = ccA[2];
                *(float2*)(COLf + (tbB + nl)*4) = make_float2(ccB[0], ccB[1]);
                COLf[(tbB + nl)*4 + 2] = ccB[2];
            }
        }
    }

    __syncthreads();

    if (wv != 0) return;

    // ---- composite: wave 0 scans all 128 samples (2 per lane) ----
    float t0 = tmin + ((float)lane + 0.5f) * STEP;
    float t1 = tmin + ((float)(lane + 64) + 0.5f) * STEP;
    bool  m0 = hit && (t0 <= tmax);
    bool  m1 = hit && (t1 <= tmax);
    float sig0 = m0 ? fmaxf(SIGf[lane], 0.f) : 0.f;
    float sig1 = m1 ? fmaxf(SIGf[lane + 64], 0.f) : 0.f;
    float e0 = expf(-sig0 * STEP), e1 = expf(-sig1 * STEP);
    float al0 = 1.f - e0, al1 = 1.f - e1;
    float li0 = logf(e0 + 1e-10f), li1 = logf(e1 + 1e-10f);
    float incl0 = li0, incl1 = li1;
    #pragma unroll
    for (int off = 1; off < 64; off <<= 1){
        float v0 = __shfl_up(incl0, off);
        float v1 = __shfl_up(incl1, off);
        if (lane >= off){ incl0 += v0; incl1 += v1; }
    }
    float tot0 = __shfl(incl0, 63);
    float ex0 = incl0 - li0;
    float ex1 = tot0 + incl1 - li1;
    float w0 = al0 * expf(ex0);
    float w1 = al1 * expf(ex1);
    float cr0 = m0 ? COLf[lane*4+0] : 0.f;
    float cg0 = m0 ? COLf[lane*4+1] : 0.f;
    float cb0 = m0 ? COLf[lane*4+2] : 0.f;
    float cr1 = m1 ? COLf[(lane+64)*4+0] : 0.f;
    float cg1 = m1 ? COLf[(lane+64)*4+1] : 0.f;
    float cb1 = m1 ? COLf[(lane+64)*4+2] : 0.f;
    float r = w0 / (1.f + expf(-cr0)) + w1 / (1.f + expf(-cr1));
    float g = w0 / (1.f + expf(-cg0)) + w1 / (1.f + expf(-cg1));
    float b = w0 / (1.f + expf(-cb0)) + w1 / (1.f + expf(-cb1));
    float wa = w0 + w1;
    #pragma unroll
    for (int off = 32; off > 0; off >>= 1){
        r  += __shfl_xor(r,  off);
        g  += __shfl_xor(g,  off);
        b  += __shfl_xor(b,  off);
        wa += __shfl_xor(wa, off);
    }
    if (lane == 0){
        out[ray*3+0] = r + (1.f - wa);
        out[ray*3+1] = g + (1.f - wa);
        out[ray*3+2] = b + (1.f - wa);
    }
    #undef RD_A
    #undef LD_B
}

extern "C" void kernel_launch(void* const* d_in, const int* in_sizes, int n_in,
                              void* d_out, int out_size, void* d_ws, size_t ws_size,
                              hipStream_t stream){
    const float* rays_o = (const float*)d_in[0];
    const float* rays_d = (const float*)d_in[1];
    const float* G1     = (const float*)d_in[2];
    const float* F      = (const float*)d_in[3];
    bool fast = (ws_size >= WS_NEED);
    int g1b = fast ? 32768 : 0;
    prep_all<<<g1b + 31, 256, 0, stream>>>(G1, F,
                                           (const float*)d_in[4], (const float*)d_in[5],
                                           (const float*)d_in[6], (const float*)d_in[7],
                                           (const float*)d_in[8], (const float*)d_in[9],
                                           (char*)d_ws, g1b);
    if (fast)
        nerf_fused<true><<<4096, 128, 0, stream>>>(rays_o, rays_d, G1, (const char*)d_ws, (float*)d_out);
    else
        nerf_fused<false><<<4096, 128, 0, stream>>>(rays_o, rays_d, G1, (const char*)d_ws, (float*)d_out);
}

// Round 7
// 371.895 us; speedup vs baseline: 1.1772x; 1.1100x over previous
//
#include <hip/hip_runtime.h>
#include <stdint.h>

#define STEP 0.02f
#define INV_RADIUS (1.0f/1.3f)
#define RADIUS 1.3f

typedef __bf16   bf16x8 __attribute__((ext_vector_type(8)));
typedef float    f32x4  __attribute__((ext_vector_type(4)));
typedef float    f32x2  __attribute__((ext_vector_type(2)));
typedef uint32_t u32x4  __attribute__((ext_vector_type(4)));
typedef uint32_t u32x4a __attribute__((ext_vector_type(4), aligned(8)));

// ---------------- ws layout (bytes) ----------------
#define FT_OFF   0         // F transposed bf16 [z16][y16][x16][c32] = 262144 B
#define W0_OFF   262144    // sig W0  K=32  N=128 : 1kk x 8nt  = 8192 B
#define W1_OFF   270336    // sig W1  K=128 N=128 : 4kk x 8nt  = 32768 B
#define W2_OFF   303104    // sig W2  K=128 N=16  : 4kk x 1nt  = 4096 B
#define C0_OFF   307200    // col W0  K=31->32 (pad at k=16) N=64 : 1x4 = 4096 B
#define C1_OFF   311296    // col W1  K=64 N=64 : 2x4          = 8192 B
#define C2_OFF   319488    // col W2  K=64 N=3->16 : 2x1       = 2048 B (end 321536)
// packed G1: [z][y][x][ch0,ch1,ch2,pad] bf16 = 8 B/cell, 256^3 cells
#define G1T_OFF  321536
#define WS_NEED  (321536ull + 134217728ull)

// ---------------- block LDS (bytes) ----------------
#define FE_BYTES  4096     // per wave: 64 rows x 64B
#define SIG_OFF   8192     // 128 f32 = 512
#define COL_OFF   8704     // 128 x 4 f32 = 2048
#define BLOCK_LDS 10752

__device__ __forceinline__ uint32_t pack2(float a, float b){
    uint32_t ua = __float_as_uint(a); ua += 0x7FFFu + ((ua>>16)&1u);
    uint32_t ub = __float_as_uint(b); ub += 0x7FFFu + ((ub>>16)&1u);
    return (ua>>16) | (ub & 0xFFFF0000u);
}
__device__ __forceinline__ float bfl(uint32_t u){ return __uint_as_float(u << 16); }
__device__ __forceinline__ float bfh(uint32_t u){ return __uint_as_float(u & 0xFFFF0000u); }
__device__ __forceinline__ void toidx(float c, float sizem1, int isize,
                                      int& i0, int& i1, float& w){
    float t = (c + 1.f) * 0.5f * sizem1;
    t = fminf(fmaxf(t, 0.f), sizem1);
    float f = floorf(t);
    i0 = (int)f;
    i1 = i0 + 1; if (i1 > isize - 1) i1 = isize - 1;
    w = t - f;
}
__device__ __forceinline__ void lds_fence(){
    asm volatile("s_waitcnt lgkmcnt(0)" ::: "memory");
}
__device__ __forceinline__ uint32_t cvtpk(float lo, float hi){
    uint32_t r;
    asm("v_cvt_pk_bf16_f32 %0, %1, %2" : "=v"(r) : "v"(lo), "v"(hi));
    return r;
}
__device__ __forceinline__ void p32swap(uint32_t& a, uint32_t& b){
    asm("v_permlane32_swap_b32 %0, %1" : "+v"(a), "+v"(b));
}
__device__ __forceinline__ void p16swap(uint32_t& a, uint32_t& b){
    asm("v_permlane16_swap_b32 %0, %1" : "+v"(a), "+v"(b));
}
__device__ __forceinline__ uint32_t pkrelu(float a, float b){
    return cvtpk(fmaxf(a, 0.f), fmaxf(b, 0.f));
}
__device__ __forceinline__ bf16x8 frag_from(uint32_t a, uint32_t b, uint32_t c, uint32_t d){
    union { u32x4 u; bf16x8 h; } cv;
    cv.u = (u32x4){a, b, c, d};
    return cv.h;
}
// D-tiles -> next-layer B-frag in-register transpose (+relu)
__device__ __forceinline__ bf16x8 xpose4(const f32x4& t0, const f32x4& t1){
    uint32_t A = pkrelu(t0[0], t0[1]);
    uint32_t B = pkrelu(t0[2], t0[3]);
    uint32_t C = pkrelu(t1[0], t1[1]);
    uint32_t D = pkrelu(t1[2], t1[3]);
    p32swap(A, C); p16swap(A, C);
    p32swap(B, D); p16swap(B, D);
    return frag_from(A, B, C, D);
}
// x-lerp of one packed (z,y)-row: cells A(dwords 0,1) B(dwords 2,3); xe => x0==255
__device__ __forceinline__ void rowlerp(const u32x4a d, bool xe, float wx,
                                        float& v0, float& v1, float& v2){
    uint32_t a01 = xe ? d[2] : d[0];
    uint32_t a2w = xe ? d[3] : d[1];
    float a0 = bfl(a01), a1 = bfh(a01), a2 = bfl(a2w);
    float b0 = bfl(d[2]), b1 = bfh(d[2]), b2 = bfl(d[3]);
    v0 = a0 + (b0 - a0)*wx;
    v1 = a1 + (b1 - a1)*wx;
    v2 = a2 + (b2 - a2)*wx;
}

// ---------------- unified prep: [0,g1b) g1-pack | [g1b,g1b+16) F | [g1b+16,g1b+31) W ----------------
__global__ __launch_bounds__(256)
void prep_all(const float* __restrict__ G1, const float* __restrict__ F,
              const float* __restrict__ W0, const float* __restrict__ W1,
              const float* __restrict__ W2, const float* __restrict__ Wc0,
              const float* __restrict__ Wc1, const float* __restrict__ Wc2,
              char* __restrict__ ws, int g1b){
    int bid = blockIdx.x, tid = threadIdx.x;
    if (bid < g1b){
        // pack G1 (3,256^3) f32 -> [z][y][x][4 bf16]; nontemporal reads so the
        // 192MB f32 stream doesn't evict the G1T pack we're writing into L3.
        int idx2 = (bid*256 + tid)*2;
        f32x2 a = __builtin_nontemporal_load((const f32x2*)(G1 + idx2));
        f32x2 b = __builtin_nontemporal_load((const f32x2*)(G1 + idx2 + 16777216));
        f32x2 c = __builtin_nontemporal_load((const f32x2*)(G1 + idx2 + 33554432));
        uint4 o = make_uint4(pack2(a[0], b[0]), pack2(c[0], 0.f),
                             pack2(a[1], b[1]), pack2(c[1], 0.f));
        *(uint4*)((uint32_t*)(ws + G1T_OFF) + idx2*2) = o;
        return;
    }
    if (bid < g1b + 16){
        // transpose F (32,16,16,16) -> bf16 [z][y][x][c]
        int idx = (bid - g1b)*256 + tid;
        uint32_t o[16];
        #pragma unroll
        for (int ch = 0; ch < 16; ch++){
            float a = F[(2*ch  )*4096 + idx];
            float b = F[(2*ch+1)*4096 + idx];
            o[ch] = pack2(a, b);
        }
        uint4* dst = (uint4*)(ws + FT_OFF);
        #pragma unroll
        for (int q = 0; q < 4; q++)
            dst[idx*4 + q] = make_uint4(o[q*4], o[q*4+1], o[q*4+2], o[q*4+3]);
        return;
    }
    // weights -> bf16 MFMA fragment layout
    // frag (kk,nt): lane l holds Wt[k = kk*32 + (l>>4)*8 + j][n = nt*16 + (l&15)], j=0..7.
    int gid = (bid - g1b - 16)*256 + tid;
    if (gid >= 58*64) return;
    int cg = gid >> 6, lane = gid & 63;
    const float* src; int K, N, base_cg, dstoff;
    if      (cg < 8)  { src = W0;  K = 32;  N = 128; base_cg = 0;  dstoff = W0_OFF; }
    else if (cg < 40) { src = W1;  K = 128; N = 128; base_cg = 8;  dstoff = W1_OFF; }
    else if (cg < 44) { src = W2;  K = 128; N = 16;  base_cg = 40; dstoff = W2_OFF; }
    else if (cg < 48) { src = Wc0; K = 31;  N = 64;  base_cg = 44; dstoff = C0_OFF; }
    else if (cg < 56) { src = Wc1; K = 64;  N = 64;  base_cg = 48; dstoff = C1_OFF; }
    else              { src = Wc2; K = 64;  N = 3;   base_cg = 56; dstoff = C2_OFF; }
    bool c0remap = (cg >= 44 && cg < 48);
    int local = cg - base_cg;
    int NT = (N + 15) >> 4;
    int nt = local % NT, kk = local / NT;
    int n = nt*16 + (lane & 15);
    int kbase = kk*32 + (lane >> 4)*8;
    uint32_t o[4];
    #pragma unroll
    for (int jj = 0; jj < 4; jj++){
        int k0 = kbase + jj*2, k1 = k0 + 1;
        int k0s = (c0remap && k0 > 16) ? k0 - 1 : k0;
        int k1s = (c0remap && k1 > 16) ? k1 - 1 : k1;
        bool v0 = (n < N) && (k0s < K) && !(c0remap && k0 == 16);
        bool v1 = (n < N) && (k1s < K) && !(c0remap && k1 == 16);
        float a = v0 ? src[k0s*N + n] : 0.f;
        float b = v1 ? src[k1s*N + n] : 0.f;
        o[jj] = pack2(a, b);
    }
    uint4* dst = (uint4*)(ws + dstoff);
    dst[local*64 + lane] = make_uint4(o[0], o[1], o[2], o[3]);
}

// ---------------- fused main: one BLOCK per ray, one WAVE per 64-sample half ----------------
// Single-tile MLP (VGPR ~64 -> 8 waves/SIMD cap): TLP beats dual-tile ILP here (R6 A/B).
template<bool G1PACK>
__global__ __launch_bounds__(128, 2)
void nerf_fused(const float* __restrict__ rays_o, const float* __restrict__ rays_d,
                const float* __restrict__ G1, const char* __restrict__ ws,
                float* __restrict__ out){
    __shared__ __align__(16) char smem[BLOCK_LDS];
    const int tid  = threadIdx.x;
    const int wv   = tid >> 6;
    const int lane = tid & 63;
    const int nl   = lane & 15;
    const int quad = lane >> 4;
    const int ray  = blockIdx.x;
    char*  FEB  = smem + wv*FE_BYTES;
    float* SIGf = (float*)(smem + SIG_OFF);
    float* COLf = (float*)(smem + COL_OFF);

    // ---- ray setup (uniform per block) ----
    float ox = rays_o[ray*3+0], oy = rays_o[ray*3+1], oz = rays_o[ray*3+2];
    float rx = rays_d[ray*3+0], ry = rays_d[ray*3+1], rz = rays_d[ray*3+2];
    float nrm = sqrtf(rx*rx + ry*ry + rz*rz);
    float dx = rx/nrm, dy = ry/nrm, dz = rz/nrm;
    float bq = ox*dx + oy*dy + oz*dz;
    float cq = ox*ox + oy*oy + oz*oz - RADIUS*RADIUS;
    float disc = bq*bq - cq;
    bool  hit = disc > 0.f;
    float sq   = sqrtf(hit ? disc : 1.f);
    float tmin = hit ? fmaxf(-bq - sq, 0.f) : 0.f;
    float tmax = hit ? (-bq + sq) : 0.f;

    // ---- SH enc of ray dir -> per-lane packed bf16 words (B-frag quads 0,1 of CIN) ----
    uint32_t encw0, encw1, encw2, encw3, cinmask;
    {
        float xx=dx*dx, yy=dy*dy, zz=dz*dz, xy=dx*dy, yz=dy*dz, xz=dx*dz;
        float sh0 = 0.28209479177387814f;
        float sh1 = -0.48860251190291987f*dy;
        float sh2 =  0.48860251190291987f*dz;
        float sh3 = -0.48860251190291987f*dx;
        float sh4 =  1.0925484305920792f*xy;
        float sh5 = -1.0925484305920792f*yz;
        float sh6 =  0.94617469575756f*zz - 0.31539156525252f;
        float sh7 = -1.0925484305920792f*xz;
        float sh8 =  0.5462742152960396f*(xx-yy);
        float sh9 =  0.5900435899266435f*dy*(-3.f*xx+yy);
        float sh10 = 2.890611442640554f*xy*dz;
        float sh11 = 0.4570457994644657f*dy*(1.f-5.f*zz);
        float sh12 = 0.3731763325901154f*dz*(5.f*zz-3.f);
        float sh13 = 0.4570457994644657f*dx*(1.f-5.f*zz);
        float sh14 = 1.445305721320277f*dz*(xx-yy);
        float sh15 = 0.5900435899266435f*dx*(-xx+3.f*yy);
        bool q0 = (quad == 0);
        encw0 = q0 ? pack2(sh0, sh1) : pack2(sh8,  sh9);
        encw1 = q0 ? pack2(sh2, sh3) : pack2(sh10, sh11);
        encw2 = q0 ? pack2(sh4, sh5) : pack2(sh12, sh13);
        encw3 = q0 ? pack2(sh6, sh7) : pack2(sh14, sh15);
        cinmask = (quad == 2) ? 0xFFFF0000u : 0xFFFFFFFFu;
    }

    const char* pW0 = ws + W0_OFF; const char* pW1 = ws + W1_OFF; const char* pW2 = ws + W2_OFF;
    const char* pC0 = ws + C0_OFF; const char* pC1 = ws + C1_OFF; const char* pC2 = ws + C2_OFF;
    const f32x4 vzero = {0.f, 0.f, 0.f, 0.f};

    #define RD_A(bp, linRow, m) \
        (*(const bf16x8*)((bp) + (linRow)*64 + ((quad ^ (((m)>>1)&3))*16)))
    #define LD_B(base, kk, NT, nt) \
        (*(const bf16x8*)((base) + (((kk)*(NT) + (nt))*64 + lane)*16))

    float Dn = (tmax - tmin) * (1.0f/STEP);
    int nv = (int)fminf(128.f, fmaxf(0.f, floorf(Dn + 0.5f) + 1.f));
    int rem = nv - wv*64;
    if (rem > 64) rem = 64;

    if (rem > 0){
        {   // ---- gather: lane gathers sample p = wv*64 + lane (if valid) ----
            if (lane < rem){
                int p = wv*64 + lane;
                float tmid = tmin + ((float)p + 0.5f) * STEP;
                float px = (ox + dx*tmid) * INV_RADIUS;
                float py = (oy + dy*tmid) * INV_RADIUS;
                float pz = (oz + dz*tmid) * INV_RADIUS;
                int x0,x1,y0,y1,z0,z1; float wx,wy,wz;
                toidx(px, 255.f, 256, x0, x1, wx);
                toidx(py, 255.f, 256, y0, y1, wy);
                toidx(pz, 255.f, 256, z0, z1, wz);
                float g1v[3];
                if constexpr (G1PACK){
                    const uint32_t* Gt = (const uint32_t*)(ws + G1T_OFF);
                    int xs = (x0 < 255) ? x0 : 254;
                    bool xe = (x0 == 255);
                    int r00 = (z0*256 + y0)*256 + xs, r01 = (z0*256 + y1)*256 + xs;
                    int r10 = (z1*256 + y0)*256 + xs, r11 = (z1*256 + y1)*256 + xs;
                    u32x4a d00 = *(const u32x4a*)(Gt + (size_t)r00*2);
                    u32x4a d01 = *(const u32x4a*)(Gt + (size_t)r01*2);
                    u32x4a d10 = *(const u32x4a*)(Gt + (size_t)r10*2);
                    u32x4a d11 = *(const u32x4a*)(Gt + (size_t)r11*2);
                    float v00x,v00y,v00z, v01x,v01y,v01z, v10x,v10y,v10z, v11x,v11y,v11z;
                    rowlerp(d00, xe, wx, v00x, v00y, v00z);
                    rowlerp(d01, xe, wx, v01x, v01y, v01z);
                    rowlerp(d10, xe, wx, v10x, v10y, v10z);
                    rowlerp(d11, xe, wx, v11x, v11y, v11z);
                    float c0x = v00x + (v01x - v00x)*wy, c1x = v10x + (v11x - v10x)*wy;
                    float c0y = v00y + (v01y - v00y)*wy, c1y = v10y + (v11y - v10y)*wy;
                    float c0z = v00z + (v01z - v00z)*wy, c1z = v10z + (v11z - v10z)*wy;
                    g1v[0] = c0x + (c1x - c0x)*wz;
                    g1v[1] = c0y + (c1y - c0y)*wz;
                    g1v[2] = c0z + (c1z - c0z)*wz;
                } else {
                    #pragma unroll
                    for (int ch = 0; ch < 3; ch++){
                        const float* gp = G1 + ch*16777216;
                        int b00 = (z0*256 + y0)*256, b01 = (z0*256 + y1)*256;
                        int b10 = (z1*256 + y0)*256, b11 = (z1*256 + y1)*256;
                        float c000 = gp[b00+x0], c001 = gp[b00+x1];
                        float c010 = gp[b01+x0], c011 = gp[b01+x1];
                        float c100 = gp[b10+x0], c101 = gp[b10+x1];
                        float c110 = gp[b11+x0], c111 = gp[b11+x1];
                        float c00 = c000 + (c001-c000)*wx;
                        float c01 = c010 + (c011-c010)*wx;
                        float c10 = c100 + (c101-c100)*wx;
                        float c11 = c110 + (c111-c110)*wx;
                        float c0 = c00 + (c01-c00)*wy;
                        float c1 = c10 + (c11-c10)*wy;
                        g1v[ch] = c0 + (c1-c0)*wz;
                    }
                }
                int fx0,fx1,fy0,fy1,fz0,fz1; float fwx,fwy,fwz;
                toidx(g1v[0], 15.f, 16, fx0, fx1, fwx);
                toidx(g1v[1], 15.f, 16, fy0, fy1, fwy);
                toidx(g1v[2], 15.f, 16, fz0, fz1, fwz);
                float feats[32];
                #pragma unroll
                for (int i = 0; i < 32; i++) feats[i] = 0.f;
                const uint4* Ft = (const uint4*)(ws + FT_OFF);
                #pragma unroll 2
                for (int corner = 0; corner < 8; corner++){
                    int cz = (corner>>2)&1, cy = (corner>>1)&1, cx = corner&1;
                    int xi = cx?fx1:fx0, yi = cy?fy1:fy0, zi = cz?fz1:fz0;
                    float w = (cx?fwx:1.f-fwx) * (cy?fwy:1.f-fwy) * (cz?fwz:1.f-fwz);
                    const uint4* cp = Ft + ((zi*16 + yi)*16 + xi)*4;
                    #pragma unroll
                    for (int q = 0; q < 4; q++){
                        uint4 v = cp[q];
                        uint32_t u[4] = {v.x, v.y, v.z, v.w};
                        #pragma unroll
                        for (int e = 0; e < 4; e++){
                            feats[q*8 + e*2    ] += w * __uint_as_float(u[e] << 16);
                            feats[q*8 + e*2 + 1] += w * __uint_as_float(u[e] & 0xFFFF0000u);
                        }
                    }
                }
                int fsw = (lane>>1)&3;
                #pragma unroll
                for (int c = 0; c < 4; c++){
                    uint4 v = make_uint4(pack2(feats[c*8+0], feats[c*8+1]),
                                         pack2(feats[c*8+2], feats[c*8+3]),
                                         pack2(feats[c*8+4], feats[c*8+5]),
                                         pack2(feats[c*8+6], feats[c*8+7]));
                    *(uint4*)(FEB + lane*64 + ((c^fsw)*16)) = v;
                }
            }
        }
        lds_fence();   // FE visible within wave

        // small head weights (loaded after gather: no liveness across gather)
        bf16x8 bW2[4], bC0[4], bC2[2];
        #pragma unroll
        for (int kk = 0; kk < 4; kk++) bW2[kk] = LD_B(pW2, kk, 1, 0);
        #pragma unroll
        for (int nt = 0; nt < 4; nt++) bC0[nt] = LD_B(pC0, 0, 4, nt);
        #pragma unroll
        for (int kk = 0; kk < 2; kk++) bC2[kk] = LD_B(pC2, kk, 1, 0);

        int mtmax = (rem + 15) >> 4;
        #pragma unroll 1
        for (int mt = 0; mt < mtmax; mt++){
            const int mArow = mt*16 + nl;
            const int tb = wv*64 + mt*16;

            // L0: W0^T(128x32) x feats(32x16)  (W-frag as A, activations as B)
            bf16x8 fe = RD_A(FEB, mArow, mArow);
            f32x4 a0[8];
            #pragma unroll
            for (int nt = 0; nt < 8; nt++)
                a0[nt] = __builtin_amdgcn_mfma_f32_16x16x32_bf16(LD_B(pW0,0,8,nt), fe, vzero, 0,0,0);
            bf16x8 h1[4];
            #pragma unroll
            for (int kk = 0; kk < 4; kk++)
                h1[kk] = xpose4(a0[2*kk], a0[2*kk+1]);   // relu + in-register transpose

            // L1: 128x128
            f32x4 a1[8];
            #pragma unroll
            for (int nt = 0; nt < 8; nt++) a1[nt] = vzero;
            #pragma unroll
            for (int kk = 0; kk < 4; kk++)
                #pragma unroll
                for (int nt = 0; nt < 8; nt++)
                    a1[nt] = __builtin_amdgcn_mfma_f32_16x16x32_bf16(LD_B(pW1,kk,8,nt), h1[kk], a1[nt], 0,0,0);
            bf16x8 h2[4];
            #pragma unroll
            for (int kk = 0; kk < 4; kk++)
                h2[kk] = xpose4(a1[2*kk], a1[2*kk+1]);

            // L2: sigma head 16x128 (no relu)
            f32x4 sacc = vzero;
            #pragma unroll
            for (int kk = 0; kk < 4; kk++)
                sacc = __builtin_amdgcn_mfma_f32_16x16x32_bf16(bW2[kk], h2[kk], sacc, 0,0,0);
            if (quad == 0) SIGf[tb + nl] = sacc[0];

            // CIN B-frag: quads 0,1 = SH enc; quads 2,3 = sig_out[1:16] (pad k=16)
            uint32_t ca = cvtpk(sacc[0], sacc[1]);
            uint32_t cb = cvtpk(sacc[2], sacc[3]);
            p32swap(ca, cb); p16swap(ca, cb);
            uint32_t cw0 = encw0, cw2 = encw2;
            p32swap(cw0, ca);
            p32swap(cw2, cb);
            cw0 &= cinmask;
            uint32_t cw1 = (quad < 2) ? encw1 : ca;
            uint32_t cw3 = (quad < 2) ? encw3 : cb;
            bf16x8 cin = frag_from(cw0, cw1, cw2, cw3);

            // C0: 64x32
            f32x4 c0[4];
            #pragma unroll
            for (int nt = 0; nt < 4; nt++)
                c0[nt] = __builtin_amdgcn_mfma_f32_16x16x32_bf16(bC0[nt], cin, vzero, 0,0,0);
            bf16x8 g1[2];
            #pragma unroll
            for (int kk = 0; kk < 2; kk++)
                g1[kk] = xpose4(c0[2*kk], c0[2*kk+1]);

            // C1: 64x64
            f32x4 c1[4];
            #pragma unroll
            for (int nt = 0; nt < 4; nt++) c1[nt] = vzero;
            #pragma unroll
            for (int kk = 0; kk < 2; kk++)
                #pragma unroll
                for (int nt = 0; nt < 4; nt++)
                    c1[nt] = __builtin_amdgcn_mfma_f32_16x16x32_bf16(LD_B(pC1,kk,4,nt), g1[kk], c1[nt], 0,0,0);
            bf16x8 g2[2];
            #pragma unroll
            for (int kk = 0; kk < 2; kk++)
                g2[kk] = xpose4(c1[2*kk], c1[2*kk+1]);

            // C2: color head (no relu); rows 0..2 = r,g,b on quad0
            f32x4 cc = vzero;
            #pragma unroll
            for (int kk = 0; kk < 2; kk++)
                cc = __builtin_amdgcn_mfma_f32_16x16x32_bf16(bC2[kk], g2[kk], cc, 0,0,0);
            if (quad == 0){
                *(float2*)(COLf + (tb + nl)*4) = make_float2(cc[0], cc[1]);
                COLf[(tb + nl)*4 + 2] = cc[2];
            }
        }
    }

    __syncthreads();

    if (wv != 0) return;

    // ---- composite: wave 0 scans all 128 samples (2 per lane) ----
    float t0 = tmin + ((float)lane + 0.5f) * STEP;
    float t1 = tmin + ((float)(lane + 64) + 0.5f) * STEP;
    bool  m0 = hit && (t0 <= tmax);
    bool  m1 = hit && (t1 <= tmax);
    float sig0 = m0 ? fmaxf(SIGf[lane], 0.f) : 0.f;
    float sig1 = m1 ? fmaxf(SIGf[lane + 64], 0.f) : 0.f;
    float e0 = expf(-sig0 * STEP), e1 = expf(-sig1 * STEP);
    float al0 = 1.f - e0, al1 = 1.f - e1;
    float li0 = logf(e0 + 1e-10f), li1 = logf(e1 + 1e-10f);
    float incl0 = li0, incl1 = li1;
    #pragma unroll
    for (int off = 1; off < 64; off <<= 1){
        float v0 = __shfl_up(incl0, off);
        float v1 = __shfl_up(incl1, off);
        if (lane >= off){ incl0 += v0; incl1 += v1; }
    }
    float tot0 = __shfl(incl0, 63);
    float ex0 = incl0 - li0;
    float ex1 = tot0 + incl1 - li1;
    float w0 = al0 * expf(ex0);
    float w1 = al1 * expf(ex1);
    float cr0 = m0 ? COLf[lane*4+0] : 0.f;
    float cg0 = m0 ? COLf[lane*4+1] : 0.f;
    float cb0 = m0 ? COLf[lane*4+2] : 0.f;
    float cr1 = m1 ? COLf[(lane+64)*4+0] : 0.f;
    float cg1 = m1 ? COLf[(lane+64)*4+1] : 0.f;
    float cb1 = m1 ? COLf[(lane+64)*4+2] : 0.f;
    float r = w0 / (1.f + expf(-cr0)) + w1 / (1.f + expf(-cr1));
    float g = w0 / (1.f + expf(-cg0)) + w1 / (1.f + expf(-cg1));
    float b = w0 / (1.f + expf(-cb0)) + w1 / (1.f + expf(-cb1));
    float wa = w0 + w1;
    #pragma unroll
    for (int off = 32; off > 0; off >>= 1){
        r  += __shfl_xor(r,  off);
        g  += __shfl_xor(g,  off);
        b  += __shfl_xor(b,  off);
        wa += __shfl_xor(wa, off);
    }
    if (lane == 0){
        out[ray*3+0] = r + (1.f - wa);
        out[ray*3+1] = g + (1.f - wa);
        out[ray*3+2] = b + (1.f - wa);
    }
    #undef RD_A
    #undef LD_B
}

extern "C" void kernel_launch(void* const* d_in, const int* in_sizes, int n_in,
                              void* d_out, int out_size, void* d_ws, size_t ws_size,
                              hipStream_t stream){
    const float* rays_o = (const float*)d_in[0];
    const float* rays_d = (const float*)d_in[1];
    const float* G1     = (const float*)d_in[2];
    const float* F      = (const float*)d_in[3];
    bool fast = (ws_size >= WS_NEED);
    int g1b = fast ? 32768 : 0;
    prep_all<<<g1b + 31, 256, 0, stream>>>(G1, F,
                                           (const float*)d_in[4], (const float*)d_in[5],
                                           (const float*)d_in[6], (const float*)d_in[7],
                                           (const float*)d_in[8], (const float*)d_in[9],
                                           (char*)d_ws, g1b);
    if (fast)
        nerf_fused<true><<<4096, 128, 0, stream>>>(rays_o, rays_d, G1, (const char*)d_ws, (float*)d_out);
    else
        nerf_fused<false><<<4096, 128, 0, stream>>>(rays_o, rays_d, G1, (const char*)d_ws, (float*)d_out);
}